// Round 3
// baseline (218.770 us; speedup 1.0000x reference)
//
#include <hip/hip_runtime.h>
#include <hip/hip_bf16.h>

#define B_ 4
#define C_ 512
#define L_ 2048
#define H_ 8
#define D_ 64
#define EPS_ 1e-5f

using short8 = __attribute__((ext_vector_type(8))) short;
using s4v    = __attribute__((ext_vector_type(4))) short;
using f32x4  = __attribute__((ext_vector_type(4))) float;
using f32x16 = __attribute__((ext_vector_type(16))) float;
using uint2v = __attribute__((ext_vector_type(2))) unsigned int;

static __device__ __forceinline__ short f2bf(float f) {
  __hip_bfloat16 h = __float2bfloat16(f);
  return __builtin_bit_cast(short, h);
}
static __device__ __forceinline__ float bf2f(short s) {
  return __bfloat162float(__builtin_bit_cast(__hip_bfloat16, s));
}
// pack two f32 -> one dword of 2 bf16 (RNE), element0 = lo
static __device__ __forceinline__ unsigned cvtpk(float lo, float hi) {
  unsigned d;
  asm("v_cvt_pk_bf16_f32 %0, %1, %2" : "=v"(d) : "v"(lo), "v"(hi));
  return d;
}
// exchange: vdst.hi-half <-> vsrc.lo-half   (r[0]=new a, r[1]=new b)
static __device__ __forceinline__ void pl32swap(unsigned& a, unsigned& b) {
  uint2v r = __builtin_amdgcn_permlane32_swap(a, b, false, false);
  a = r[0]; b = r[1];
}
static __device__ __forceinline__ short8 mk8(unsigned w0, unsigned w1, unsigned w2, unsigned w3) {
  union { unsigned u[4]; short8 s; } u;
  u.u[0] = w0; u.u[1] = w1; u.u[2] = w2; u.u[3] = w3;
  return u.s;
}
// async global->LDS, 16B per lane; lds dest = wave-uniform base + lane*16
static __device__ __forceinline__ void gload16(const void* g, void* l) {
  __builtin_amdgcn_global_load_lds(
      (const __attribute__((address_space(1))) unsigned int*)g,
      (__attribute__((address_space(3))) unsigned int*)l, 16, 0, 0);
}

// ---------------- Kernel 1: convert weights fp32 [in][out] -> bf16 [out][in] ----
__global__ __launch_bounds__(256) void k_convert_w(
    const float* __restrict__ Wq, const float* __restrict__ Wk,
    const float* __restrict__ Wv, const float* __restrict__ Wo,
    short* __restrict__ Wt) {
  int m = blockIdx.x, k0 = blockIdx.y * 32, n0 = blockIdx.z * 32;
  const float* W = (m == 0) ? Wq : (m == 1) ? Wk : (m == 2) ? Wv : Wo;
  __shared__ float T[32][33];
  int t = threadIdx.x;
  {
    int kl = t >> 3, n4 = (t & 7) * 4;
    float4 v = *(const float4*)(W + (size_t)(k0 + kl) * C_ + n0 + n4);
    T[kl][n4] = v.x; T[kl][n4 + 1] = v.y; T[kl][n4 + 2] = v.z; T[kl][n4 + 3] = v.w;
  }
  __syncthreads();
  {
    int nl = t >> 3, k4 = (t & 7) * 4;
    s4v o;
#pragma unroll
    for (int j = 0; j < 4; ++j) o[j] = f2bf(T[k4 + j][nl]);
    *(s4v*)(Wt + (size_t)(m * C_ + n0 + nl) * C_ + k0 + k4) = o;   // Wt[m][n][k]
  }
}

// ---------------- Kernel 2: transpose + pos + LayerNorm -> bf16 (B,L,C) --------
__global__ __launch_bounds__(256) void k_prep(
    const float* __restrict__ query, const float* __restrict__ kv,
    const float* __restrict__ pos,
    const float* __restrict__ qg, const float* __restrict__ qb,
    const float* __restrict__ kg, const float* __restrict__ kb,
    short* __restrict__ qn, short* __restrict__ kvn) {
  int l0 = blockIdx.x * 16;
  int b  = blockIdx.y;
  int z  = blockIdx.z;
  const float* src = z ? kv : query;
  const float* g   = z ? kg : qg;
  const float* be  = z ? kb : qb;
  short* dst       = z ? kvn : qn;

  __shared__ float T[16][516];
  __shared__ float mu_s[16], rs_s[16];
  int t = threadIdx.x;

  for (int i = 0; i < 32; ++i) {
    int flat = i * 256 + t;
    int c = flat >> 4, ll = flat & 15;
    T[ll][c] = src[(size_t)(b * C_ + c) * L_ + l0 + ll];
  }
  __syncthreads();
  for (int i = 0; i < 32; ++i) {
    int flat = i * 256 + t;
    int ll = flat >> 9, c = flat & 511;
    T[ll][c] += pos[(size_t)(l0 + ll) * C_ + c];
  }
  __syncthreads();
  {
    int row = t >> 4, j = t & 15;
    float s1 = 0.f, s2 = 0.f;
    for (int c = j; c < C_; c += 16) { float v = T[row][c]; s1 += v; s2 += v * v; }
    for (int m = 1; m < 16; m <<= 1) {
      s1 += __shfl_xor(s1, m, 64);
      s2 += __shfl_xor(s2, m, 64);
    }
    if (j == 0) {
      float mu  = s1 * (1.0f / C_);
      float var = s2 * (1.0f / C_) - mu * mu;
      mu_s[row] = mu;
      rs_s[row] = rsqrtf(var + EPS_);
    }
  }
  __syncthreads();
  for (int i = 0; i < 32; ++i) {
    int flat = i * 256 + t;
    int ll = flat >> 9, c = flat & 511;
    float v = (T[ll][c] - mu_s[ll]) * rs_s[ll] * g[c] + be[c];
    dst[(size_t)(b * L_ + l0 + ll) * C_ + c] = f2bf(v);
  }
}

// ---------------- Kernel 3: fused QKV projection GEMM (m97-style staging) -------
// Q output is pre-scaled by 0.125*log2(e) so k_attn can use exp2 with no mul.
__global__ __launch_bounds__(256) void k_gemm_qkv(
    const short* __restrict__ qn, const short* __restrict__ kvn,
    const short* __restrict__ Wt,
    const float* __restrict__ bq, const float* __restrict__ bk, const float* __restrict__ bv,
    short* __restrict__ Qw, short* __restrict__ Kw, short* __restrict__ Vw) {
  int z = blockIdx.z;
  const short* X    = z ? kvn : qn;
  const short* W    = Wt + (size_t)z * C_ * C_;
  const float* bias = (z == 0) ? bq : (z == 1) ? bk : bv;
  short* Y          = (z == 0) ? Qw : (z == 1) ? Kw : Vw;
  float sc          = (z == 0) ? 0.18033688011112042f : 1.0f;  // 0.125*log2(e)

  int m0 = blockIdx.x * 128, n0 = blockIdx.y * 128;
  __shared__ alignas(16) short As[128 * 32];   // linear, global_load_lds dest
  __shared__ alignas(16) short Bs[128 * 32];
  int t = threadIdx.x, lane = t & 63, w = t >> 6;
  int wm = w & 1, wn = w >> 1;

  f32x4 zero4 = {0.f, 0.f, 0.f, 0.f};
  f32x4 acc[4][4];
  for (int i = 0; i < 4; ++i) for (int j = 0; j < 4; ++j) acc[i][j] = zero4;

  for (int k0 = 0; k0 < C_; k0 += 32) {
    __syncthreads();
#pragma unroll
    for (int j = 0; j < 2; ++j) {
      int u = j * 256 + t;                 // 16B unit within 128x32 tile
      int row = u >> 2, cs = (u & 3) * 8;  // 4 units per 32-short row
      int lb = (j * 256 + (t & ~63)) * 8;  // wave-uniform LDS base (shorts)
      gload16(X + (size_t)(m0 + row) * C_ + k0 + cs, As + lb);
      gload16(W + (size_t)(n0 + row) * C_ + k0 + cs, Bs + lb);
    }
    __syncthreads();
    short8 a[4], bf[4];
    for (int i = 0; i < 4; ++i)
      a[i]  = *(const short8*)(As + (wm * 64 + i * 16 + (lane & 15)) * 32 + ((lane >> 4) << 3));
    for (int i = 0; i < 4; ++i)
      bf[i] = *(const short8*)(Bs + (wn * 64 + i * 16 + (lane & 15)) * 32 + ((lane >> 4) << 3));
    for (int i = 0; i < 4; ++i)
      for (int j = 0; j < 4; ++j)
        acc[i][j] = __builtin_amdgcn_mfma_f32_16x16x32_bf16(a[i], bf[j], acc[i][j], 0, 0, 0);
  }

  for (int i = 0; i < 4; ++i)
    for (int j = 0; j < 4; ++j) {
      int colg = n0 + wn * 64 + j * 16 + (lane & 15);
      float bia = bias[colg];
      for (int r = 0; r < 4; ++r) {
        int rowg = m0 + wm * 64 + i * 16 + (lane >> 4) * 4 + r;
        Y[(size_t)rowg * C_ + colg] = f2bf((acc[i][j][r] + bia) * sc);
      }
    }
}

// ---------------- Kernel 3b: V -> V^T per head: Vtg[b][h][d][l] ----------------
__global__ __launch_bounds__(256) void k_transpose_v(
    const short* __restrict__ Vw, short* __restrict__ Vtg) {
  int l0 = blockIdx.x * 64, h = blockIdx.y, b = blockIdx.z;
  __shared__ alignas(16) short T[64 * 64];   // XOR-swizzled 16B chunks
  int t = threadIdx.x;
#pragma unroll
  for (int p = 0; p < 2; ++p) {
    int flat = p * 256 + t;
    int l = flat >> 3, cc = flat & 7;
    int sw = (l & 7) ^ ((l >> 3) & 7);
    *(short8*)(T + l * 64 + ((cc ^ sw) << 3)) =
        *(const short8*)(Vw + ((size_t)(b * L_ + l0 + l) * H_ + h) * D_ + (cc << 3));
  }
  __syncthreads();
#pragma unroll
  for (int p = 0; p < 2; ++p) {
    int flat = p * 256 + t;
    int d = flat >> 3, l8 = (flat & 7) * 8;
    int sw_hi = (l8 >> 3) & 7;
    short8 o;
#pragma unroll
    for (int j = 0; j < 8; ++j) {
      int pc = (d >> 3) ^ j ^ sw_hi;
      o[j] = T[(l8 + j) * 64 + (pc << 3) + (d & 7)];
    }
    *(short8*)(Vtg + ((size_t)(b * H_ + h) * D_ + d) * L_ + l0 + l8) = o;
  }
}

// ---------------- Kernel 4: attention, Q-tile 64, lr-split waves ---------------
// Grid (L/64, H, B) = 1024 blocks -> 4 blocks/CU (was 2). Wave w: owns q-block
// (w>>1)*32 and lr-subtile (w&1). Each wave: 4 QK MFMA + 16-elem softmax +
// 4 PV MFMA per 64-lr chunk (partial O over its lr half). Pair-reduce in LDS
// at epilogue. Staging/double-buffer identical to the verified 49us round-1.
#define LDK 72
#define LDV 72
__global__ __launch_bounds__(256, 4) void k_attn(
    const short* __restrict__ Qw, const short* __restrict__ Kw,
    const short* __restrict__ Vtg, short* __restrict__ Ow) {
  int l0 = blockIdx.x * 64;
  int h  = blockIdx.y;
  int b  = blockIdx.z;
  __shared__ alignas(16) short Kt[2][64 * LDK];
  __shared__ alignas(16) short Vt[2][64 * LDV];
  int t = threadIdx.x, lane = t & 63, w = t >> 6;
  int l5 = lane & 31, hi = lane >> 5;
  int qsel = w >> 1;     // which 32-q block of the 64-q tile
  int Ts   = w & 1;      // which 32-lr subtile of each 64-lr chunk

  // Q fragments (B-operand: col=q=l5, k=d). Q already scaled by 0.125*log2e.
  short8 qf[4];
  {
    int qrow = b * L_ + l0 + qsel * 32 + l5;
    const short* qp = Qw + ((size_t)qrow * H_ + h) * D_ + hi * 8;
#pragma unroll
    for (int kc = 0; kc < 4; ++kc) qf[kc] = *(const short8*)(qp + kc * 16);
  }

  f32x16 acc[2];
#pragma unroll
  for (int dt = 0; dt < 2; ++dt)
#pragma unroll
    for (int r = 0; r < 16; ++r) acc[dt][r] = 0.f;
  float lsum = 0.f;

  const short* Kbase = Kw + (size_t)(b * L_) * C_ + h * D_;
  const short* Vbase = Vtg + (size_t)(b * H_ + h) * D_ * L_;

  int sr = t >> 3, sc = (t & 7) * 8;   // staging: row 0..31 (+32), 16B col chunk

  // stage chunk 0 into buffer 0
  {
    short8 kr[2], vr[2];
#pragma unroll
    for (int p = 0; p < 2; ++p) {
      kr[p] = *(const short8*)(Kbase + (size_t)(p * 32 + sr) * C_ + sc);
      vr[p] = *(const short8*)(Vbase + (size_t)(p * 32 + sr) * L_ + sc);
    }
#pragma unroll
    for (int p = 0; p < 2; ++p) {
      *(short8*)(&Kt[0][(p * 32 + sr) * LDK + sc]) = kr[p];
      *(short8*)(&Vt[0][(p * 32 + sr) * LDV + sc]) = vr[p];
    }
  }

  int cur = 0;
  for (int it = 0; it < 32; ++it) {
    __syncthreads();   // buf[cur] ready; all prior readers of buf[cur^1] done
    // issue next chunk's global loads early — they fly under this chunk's compute
    short8 kn[2], vn[2];
    if (it < 31) {
      int lr0 = (it + 1) * 64;
#pragma unroll
      for (int p = 0; p < 2; ++p) {
        kn[p] = *(const short8*)(Kbase + (size_t)(lr0 + p * 32 + sr) * C_ + sc);
        vn[p] = *(const short8*)(Vbase + (size_t)(p * 32 + sr) * L_ + lr0 + sc);
      }
    }
    const short* KT = &Kt[cur][0];
    const short* VT = &Vt[cur][0];

    // --- S^T = K . Q^T   (this wave's 32-lr subtile only)
    short8 kf[4];
#pragma unroll
    for (int kc = 0; kc < 4; ++kc)
      kf[kc] = *(const short8*)(KT + (Ts * 32 + l5) * LDK + kc * 16 + hi * 8);
    // V^T fragments for this wave's two k-slots
    short8 va[2][2];
#pragma unroll
    for (int dt = 0; dt < 2; ++dt)
#pragma unroll
      for (int kc = 0; kc < 2; ++kc)
        va[dt][kc] = *(const short8*)(VT + (dt * 32 + l5) * LDV + (Ts * 2 + kc) * 16 + hi * 8);

    f32x16 st;
#pragma unroll
    for (int r = 0; r < 16; ++r) st[r] = 0.f;
    __builtin_amdgcn_s_setprio(1);
#pragma unroll
    for (int kc = 0; kc < 4; ++kc)
      st = __builtin_amdgcn_mfma_f32_32x32x16_bf16(kf[kc], qf[kc], st, 0, 0, 0);
    __builtin_amdgcn_s_setprio(0);

    // --- softmax (unnormalized) + pack P^T B-frags in-register
    float ps[16];
#pragma unroll
    for (int r = 0; r < 16; ++r) {
      float u  = __builtin_amdgcn_fmed3f(st[r], -72.134752044448f, 72.134752044448f);
      float pv = __builtin_amdgcn_exp2f(u);
      lsum += pv;
      ps[r] = pv;
    }
    short8 pfrag[2];
    {
      unsigned d0 = cvtpk(ps[0], ps[1]),   d1 = cvtpk(ps[2], ps[3]);
      unsigned d2 = cvtpk(ps[4], ps[5]),   d3 = cvtpk(ps[6], ps[7]);
      pl32swap(d0, d2); pl32swap(d1, d3);
      pfrag[0] = mk8(d0, d1, d2, d3);
      unsigned e0 = cvtpk(ps[8], ps[9]),   e1 = cvtpk(ps[10], ps[11]);
      unsigned e2 = cvtpk(ps[12], ps[13]), e3 = cvtpk(ps[14], ps[15]);
      pl32swap(e0, e2); pl32swap(e1, e3);
      pfrag[1] = mk8(e0, e1, e2, e3);
    }

    // --- O^T(partial) += V^T . P^T
    __builtin_amdgcn_s_setprio(1);
#pragma unroll
    for (int dt = 0; dt < 2; ++dt)
#pragma unroll
      for (int kc = 0; kc < 2; ++kc)
        acc[dt] = __builtin_amdgcn_mfma_f32_32x32x16_bf16(va[dt][kc], pfrag[kc], acc[dt], 0, 0, 0);
    __builtin_amdgcn_s_setprio(0);

    // write next chunk into the other buffer (vmcnt wait lands here, post-compute)
    if (it < 31) {
#pragma unroll
      for (int p = 0; p < 2; ++p) {
        *(short8*)(&Kt[cur ^ 1][(p * 32 + sr) * LDK + sc]) = kn[p];
        *(short8*)(&Vt[cur ^ 1][(p * 32 + sr) * LDV + sc]) = vn[p];
      }
    }
    cur ^= 1;
  }

  // --- epilogue: pair-reduce (odd wave -> even wave), normalize, store --------
  __syncthreads();                       // all chunk LDS reads done; reuse Kt/Vt
  float* red = (float*)&Kt[0][0];        // 2 pairs x 64 lanes x 34 f32 = 17408 B
  if (w & 1) {
    float* dst = red + (w >> 1) * (64 * 34) + lane * 34;
#pragma unroll
    for (int dt = 0; dt < 2; ++dt)
#pragma unroll
      for (int r = 0; r < 16; ++r) dst[dt * 16 + r] = acc[dt][r];
    dst[32] = lsum;
  }
  __syncthreads();
  if (!(w & 1)) {
    const float* srcp = red + (w >> 1) * (64 * 34) + lane * 34;
#pragma unroll
    for (int dt = 0; dt < 2; ++dt)
#pragma unroll
      for (int r = 0; r < 16; ++r) acc[dt][r] += srcp[dt * 16 + r];
    lsum += srcp[32];
    lsum += __shfl_xor(lsum, 32, 64);    // combine hi halves: full row sum
    float inv = 1.0f / lsum;
    short* ot = (short*)&Vt[0][0] + (w >> 1) * (32 * 72);  // 32 q-rows x 64 d (+pad)
#pragma unroll
    for (int dt = 0; dt < 2; ++dt)
#pragma unroll
      for (int rq = 0; rq < 4; ++rq) {
        s4v o;
#pragma unroll
        for (int j = 0; j < 4; ++j) o[j] = f2bf(acc[dt][rq * 4 + j] * inv);
        *(s4v*)(ot + l5 * 72 + dt * 32 + rq * 8 + hi * 4) = o;
      }
#pragma unroll
    for (int p = 0; p < 4; ++p) {
      int rr = p * 8 + (lane >> 3);
      int c8b = (lane & 7) * 8;
      short8 v = *(const short8*)(ot + rr * 72 + c8b);
      int qg = b * L_ + l0 + (w >> 1) * 32 + rr;
      *(short8*)(Ow + ((size_t)qg * H_ + h) * D_ + c8b) = v;
    }
  }
}

// ---------------- Kernel 5: output projection + bias + residual + transpose ----
__global__ __launch_bounds__(256) void k_gemm_out(
    const short* __restrict__ Ow, const short* __restrict__ Wot,
    const float* __restrict__ bo, const short* __restrict__ qn,
    float* __restrict__ out) {
  int m0 = blockIdx.x * 128, n0 = blockIdx.y * 128;
  __shared__ alignas(16) short As[128 * 32];
  __shared__ alignas(16) short Bs[128 * 32];
  int t = threadIdx.x, lane = t & 63, w = t >> 6;
  int wm = w & 1, wn = w >> 1;

  f32x4 zero4 = {0.f, 0.f, 0.f, 0.f};
  f32x4 acc[4][4];
  for (int i = 0; i < 4; ++i) for (int j = 0; j < 4; ++j) acc[i][j] = zero4;

  for (int k0 = 0; k0 < C_; k0 += 32) {
    __syncthreads();
#pragma unroll
    for (int j = 0; j < 2; ++j) {
      int u = j * 256 + t;
      int row = u >> 2, cs = (u & 3) * 8;
      int lb = (j * 256 + (t & ~63)) * 8;
      gload16(Ow  + (size_t)(m0 + row) * C_ + k0 + cs, As + lb);
      gload16(Wot + (size_t)(n0 + row) * C_ + k0 + cs, Bs + lb);
    }
    __syncthreads();
    short8 a[4], bf[4];
    for (int i = 0; i < 4; ++i)
      a[i]  = *(const short8*)(As + (wm * 64 + i * 16 + (lane & 15)) * 32 + ((lane >> 4) << 3));
    for (int i = 0; i < 4; ++i)
      bf[i] = *(const short8*)(Bs + (wn * 64 + i * 16 + (lane & 15)) * 32 + ((lane >> 4) << 3));
    for (int i = 0; i < 4; ++i)
      for (int j = 0; j < 4; ++j)
        acc[i][j] = __builtin_amdgcn_mfma_f32_16x16x32_bf16(a[i], bf[j], acc[i][j], 0, 0, 0);
  }

  for (int i = 0; i < 4; ++i)
    for (int j = 0; j < 4; ++j) {
      int colg = n0 + wn * 64 + j * 16 + (lane & 15);
      float bia = bo[colg];
      for (int r = 0; r < 4; ++r) {
        int rowg = m0 + wm * 64 + i * 16 + (lane >> 4) * 4 + r;
        float val = acc[i][j][r] + bia + bf2f(qn[(size_t)rowg * C_ + colg]);
        int bb = rowg >> 11, l = rowg & (L_ - 1);
        out[((size_t)bb * C_ + colg) * L_ + l] = val;   // (B, C, L)
      }
    }
}

extern "C" void kernel_launch(void* const* d_in, const int* in_sizes, int n_in,
                              void* d_out, int out_size, void* d_ws, size_t ws_size,
                              hipStream_t stream) {
  const float* query     = (const float*)d_in[0];
  const float* key_value = (const float*)d_in[1];
  const float* pos       = (const float*)d_in[2];
  const float* qg        = (const float*)d_in[3];
  const float* qb        = (const float*)d_in[4];
  const float* kg        = (const float*)d_in[5];
  const float* kb        = (const float*)d_in[6];
  const float* Wq        = (const float*)d_in[7];
  const float* bq        = (const float*)d_in[8];
  const float* Wk        = (const float*)d_in[9];
  const float* bk        = (const float*)d_in[10];
  const float* Wv        = (const float*)d_in[11];
  const float* bv        = (const float*)d_in[12];
  const float* Wo        = (const float*)d_in[13];
  const float* bo        = (const float*)d_in[14];
  float* out = (float*)d_out;

  char* ws = (char*)d_ws;
  const size_t SZ = (size_t)B_ * L_ * C_ * 2;   // 8 MB per bf16 (B,L,C) buffer
  short* qn  = (short*)(ws + 0 * SZ);
  short* kvn = (short*)(ws + 1 * SZ);
  short* Qw  = (short*)(ws + 2 * SZ);
  short* Kw  = (short*)(ws + 3 * SZ);
  short* Vw  = (short*)(ws + 4 * SZ);
  short* Ow  = (short*)(ws + 5 * SZ);
  short* Wt  = (short*)(ws + 6 * SZ);           // 4 x 512x512 bf16 = 2 MB
  short* Vtg = kvn;   // kvn dead after k_gemm_qkv; reuse for V^T [b][h][d][l]

  k_convert_w<<<dim3(4, 16, 16), 256, 0, stream>>>(Wq, Wk, Wv, Wo, Wt);
  k_prep<<<dim3(L_ / 16, B_, 2), 256, 0, stream>>>(query, key_value, pos, qg, qb, kg, kb, qn, kvn);
  k_gemm_qkv<<<dim3(8192 / 128, C_ / 128, 3), 256, 0, stream>>>(qn, kvn, Wt, bq, bk, bv, Qw, Kw, Vw);
  k_transpose_v<<<dim3(L_ / 64, H_, B_), 256, 0, stream>>>(Vw, Vtg);
  k_attn<<<dim3(L_ / 64, H_, B_), 256, 0, stream>>>(Qw, Kw, Vtg, Ow);
  k_gemm_out<<<dim3(8192 / 128, C_ / 128, 1), 256, 0, stream>>>(Ow, Wt + (size_t)3 * C_ * C_, bo, qn, out);
}

// Round 4
// 213.481 us; speedup vs baseline: 1.0248x; 1.0248x over previous
//
#include <hip/hip_runtime.h>
#include <hip/hip_bf16.h>

#define B_ 4
#define C_ 512
#define L_ 2048
#define H_ 8
#define D_ 64
#define EPS_ 1e-5f

using short8 = __attribute__((ext_vector_type(8))) short;
using s4v    = __attribute__((ext_vector_type(4))) short;
using f32x4  = __attribute__((ext_vector_type(4))) float;
using f32x16 = __attribute__((ext_vector_type(16))) float;
using uint2v = __attribute__((ext_vector_type(2))) unsigned int;

static __device__ __forceinline__ short f2bf(float f) {
  __hip_bfloat16 h = __float2bfloat16(f);
  return __builtin_bit_cast(short, h);
}
static __device__ __forceinline__ float bf2f(short s) {
  return __bfloat162float(__builtin_bit_cast(__hip_bfloat16, s));
}
// pack two f32 -> one dword of 2 bf16 (RNE), element0 = lo
static __device__ __forceinline__ unsigned cvtpk(float lo, float hi) {
  unsigned d;
  asm("v_cvt_pk_bf16_f32 %0, %1, %2" : "=v"(d) : "v"(lo), "v"(hi));
  return d;
}
// exchange: vdst.hi-half <-> vsrc.lo-half   (r[0]=new a, r[1]=new b)
static __device__ __forceinline__ void pl32swap(unsigned& a, unsigned& b) {
  uint2v r = __builtin_amdgcn_permlane32_swap(a, b, false, false);
  a = r[0]; b = r[1];
}
static __device__ __forceinline__ short8 mk8(unsigned w0, unsigned w1, unsigned w2, unsigned w3) {
  union { unsigned u[4]; short8 s; } u;
  u.u[0] = w0; u.u[1] = w1; u.u[2] = w2; u.u[3] = w3;
  return u.s;
}
// async global->LDS, 16B per lane; lds dest = wave-uniform base + lane*16
static __device__ __forceinline__ void gload16(const void* g, void* l) {
  __builtin_amdgcn_global_load_lds(
      (const __attribute__((address_space(1))) unsigned int*)g,
      (__attribute__((address_space(3))) unsigned int*)l, 16, 0, 0);
}
// source-side chunk swizzle for linear gload_lds staging of [row][64-short] tiles:
// lane l stages slot (row = l>>3, c8 = l&7); slot c8 must hold global chunk
// c8 ^ (row&7)  ->  per-lane global short-offset:
#define SW8(l) (((((l) & 7) ^ (((l) >> 3) & 7))) << 3)

// ---------------- Kernel 1: convert weights fp32 [in][out] -> bf16 [out][in] ----
__global__ __launch_bounds__(256) void k_convert_w(
    const float* __restrict__ Wq, const float* __restrict__ Wk,
    const float* __restrict__ Wv, const float* __restrict__ Wo,
    short* __restrict__ Wt) {
  int m = blockIdx.x, k0 = blockIdx.y * 32, n0 = blockIdx.z * 32;
  const float* W = (m == 0) ? Wq : (m == 1) ? Wk : (m == 2) ? Wv : Wo;
  __shared__ float T[32][33];
  int t = threadIdx.x;
  {
    int kl = t >> 3, n4 = (t & 7) * 4;
    float4 v = *(const float4*)(W + (size_t)(k0 + kl) * C_ + n0 + n4);
    T[kl][n4] = v.x; T[kl][n4 + 1] = v.y; T[kl][n4 + 2] = v.z; T[kl][n4 + 3] = v.w;
  }
  __syncthreads();
  {
    int nl = t >> 3, k4 = (t & 7) * 4;
    s4v o;
#pragma unroll
    for (int j = 0; j < 4; ++j) o[j] = f2bf(T[k4 + j][nl]);
    *(s4v*)(Wt + (size_t)(m * C_ + n0 + nl) * C_ + k0 + k4) = o;   // Wt[m][n][k]
  }
}

// ---------------- Kernel 2: transpose + pos + LayerNorm -> bf16 (B,L,C) --------
// v2: 32-row tile, float4-coalesced loads along L, float4 pos add, short8 store.
__global__ __launch_bounds__(256) void k_prep(
    const float* __restrict__ query, const float* __restrict__ kv,
    const float* __restrict__ pos,
    const float* __restrict__ qg, const float* __restrict__ qb,
    const float* __restrict__ kg, const float* __restrict__ kb,
    short* __restrict__ qn, short* __restrict__ kvn) {
  int l0 = blockIdx.x * 32;
  int b  = blockIdx.y;
  int z  = blockIdx.z;
  const float* src = z ? kv : query;
  const float* g   = z ? kg : qg;
  const float* be  = z ? kb : qb;
  short* dst       = z ? kvn : qn;

  __shared__ float T[32][516];            // 66 KB
  __shared__ float mu_s[32], rs_s[32];
  int t = threadIdx.x;

  // load: thread reads float4 along L (fully coalesced 128B segments)
#pragma unroll
  for (int i = 0; i < 16; ++i) {
    int c  = i * 32 + (t >> 3);
    int lg = (t & 7) * 4;
    float4 v = *(const float4*)(src + (size_t)(b * C_ + c) * L_ + l0 + lg);
    T[lg][c] = v.x; T[lg + 1][c] = v.y; T[lg + 2][c] = v.z; T[lg + 3][c] = v.w;
  }
  __syncthreads();
  // pos add: float4 along C (coalesced)
#pragma unroll
  for (int i = 0; i < 16; ++i) {
    int flat = i * 256 + t;
    int ll = flat >> 7, c4 = (flat & 127) * 4;
    float4 p = *(const float4*)(pos + (size_t)(l0 + ll) * C_ + c4);
    float4* tp = (float4*)&T[ll][c4];
    float4 vv = *tp;
    vv.x += p.x; vv.y += p.y; vv.z += p.z; vv.w += p.w;
    *tp = vv;
  }
  __syncthreads();
  // stats: 8 threads per row, float4 strided
  {
    int row = t >> 3, j = t & 7;
    float s1 = 0.f, s2 = 0.f;
#pragma unroll
    for (int k = 0; k < 16; ++k) {
      float4 v = *(const float4*)&T[row][j * 4 + k * 32];
      s1 += v.x + v.y + v.z + v.w;
      s2 += v.x * v.x + v.y * v.y + v.z * v.z + v.w * v.w;
    }
    s1 += __shfl_xor(s1, 1, 64); s2 += __shfl_xor(s2, 1, 64);
    s1 += __shfl_xor(s1, 2, 64); s2 += __shfl_xor(s2, 2, 64);
    s1 += __shfl_xor(s1, 4, 64); s2 += __shfl_xor(s2, 4, 64);
    if (j == 0) {
      float mu  = s1 * (1.0f / C_);
      float var = s2 * (1.0f / C_) - mu * mu;
      mu_s[row] = mu;
      rs_s[row] = rsqrtf(var + EPS_);
    }
  }
  __syncthreads();
  // normalize + short8 store (coalesced along C)
#pragma unroll
  for (int i = 0; i < 8; ++i) {
    int row = i * 4 + (t >> 6);
    int c   = (t & 63) * 8;
    float mu = mu_s[row], rs = rs_s[row];
    short8 o;
#pragma unroll
    for (int jj = 0; jj < 8; ++jj) {
      float v = (T[row][c + jj] - mu) * rs * g[c + jj] + be[c + jj];
      o[jj] = f2bf(v);
    }
    *(short8*)(dst + (size_t)(b * L_ + l0 + row) * C_ + c) = o;
  }
}

// ---------------- Kernel 3: fused QKV projection GEMM, BK=64, swizzled staging --
// Q output is pre-scaled by 0.125*log2(e) so k_attn can use exp2 with no mul.
__global__ __launch_bounds__(256) void k_gemm_qkv(
    const short* __restrict__ qn, const short* __restrict__ kvn,
    const short* __restrict__ Wt,
    const float* __restrict__ bq, const float* __restrict__ bk, const float* __restrict__ bv,
    short* __restrict__ Qw, short* __restrict__ Kw, short* __restrict__ Vw) {
  int z = blockIdx.z;
  const short* X    = z ? kvn : qn;
  const short* W    = Wt + (size_t)z * C_ * C_;
  const float* bias = (z == 0) ? bq : (z == 1) ? bk : bv;
  short* Y          = (z == 0) ? Qw : (z == 1) ? Kw : Vw;
  float sc          = (z == 0) ? 0.18033688011112042f : 1.0f;  // 0.125*log2(e)

  int m0 = blockIdx.x * 128, n0 = blockIdx.y * 128;
  __shared__ alignas(16) short As[128 * 64];   // linear rows, chunk-swizzled
  __shared__ alignas(16) short Bs[128 * 64];
  int t = threadIdx.x, lane = t & 63, w = t >> 6;
  int wm = w & 1, wn = w >> 1;
  int g0 = w * 8 + (lane >> 3);
  int gc = SW8(lane);

  f32x4 zero4 = {0.f, 0.f, 0.f, 0.f};
  f32x4 acc[4][4];
  for (int i = 0; i < 4; ++i) for (int j = 0; j < 4; ++j) acc[i][j] = zero4;

  for (int k0 = 0; k0 < C_; k0 += 64) {
    __syncthreads();
#pragma unroll
    for (int i = 0; i < 4; ++i) {
      int row = i * 32 + g0;
      gload16(X + (size_t)(m0 + row) * C_ + k0 + gc, As + (i * 4 + w) * 512);
      gload16(W + (size_t)(n0 + row) * C_ + k0 + gc, Bs + (i * 4 + w) * 512);
    }
    __syncthreads();
#pragma unroll
    for (int kk = 0; kk < 2; ++kk) {
      short8 a[4], bf[4];
#pragma unroll
      for (int i = 0; i < 4; ++i) {
        int row = wm * 64 + i * 16 + (lane & 15);
        a[i] = *(const short8*)(As + row * 64 + (((kk * 4 + (lane >> 4)) ^ (row & 7)) << 3));
      }
#pragma unroll
      for (int i = 0; i < 4; ++i) {
        int row = wn * 64 + i * 16 + (lane & 15);
        bf[i] = *(const short8*)(Bs + row * 64 + (((kk * 4 + (lane >> 4)) ^ (row & 7)) << 3));
      }
#pragma unroll
      for (int i = 0; i < 4; ++i)
#pragma unroll
        for (int j = 0; j < 4; ++j)
          acc[i][j] = __builtin_amdgcn_mfma_f32_16x16x32_bf16(a[i], bf[j], acc[i][j], 0, 0, 0);
    }
  }

  for (int i = 0; i < 4; ++i)
    for (int j = 0; j < 4; ++j) {
      int colg = n0 + wn * 64 + j * 16 + (lane & 15);
      float bia = bias[colg];
      for (int r = 0; r < 4; ++r) {
        int rowg = m0 + wm * 64 + i * 16 + (lane >> 4) * 4 + r;
        Y[(size_t)rowg * C_ + colg] = f2bf((acc[i][j][r] + bia) * sc);
      }
    }
}

// ---------------- Kernel 3b: V -> V^T per head: Vtg[b][h][d][l] ----------------
__global__ __launch_bounds__(256) void k_transpose_v(
    const short* __restrict__ Vw, short* __restrict__ Vtg) {
  int l0 = blockIdx.x * 64, h = blockIdx.y, b = blockIdx.z;
  __shared__ alignas(16) short T[64 * 64];   // XOR-swizzled 16B chunks
  int t = threadIdx.x;
#pragma unroll
  for (int p = 0; p < 2; ++p) {
    int flat = p * 256 + t;
    int l = flat >> 3, cc = flat & 7;
    int sw = (l & 7) ^ ((l >> 3) & 7);
    *(short8*)(T + l * 64 + ((cc ^ sw) << 3)) =
        *(const short8*)(Vw + ((size_t)(b * L_ + l0 + l) * H_ + h) * D_ + (cc << 3));
  }
  __syncthreads();
#pragma unroll
  for (int p = 0; p < 2; ++p) {
    int flat = p * 256 + t;
    int d = flat >> 3, l8 = (flat & 7) * 8;
    int sw_hi = (l8 >> 3) & 7;
    short8 o;
#pragma unroll
    for (int j = 0; j < 8; ++j) {
      int pc = (d >> 3) ^ j ^ sw_hi;
      o[j] = T[(l8 + j) * 64 + (pc << 3) + (d & 7)];
    }
    *(short8*)(Vtg + ((size_t)(b * H_ + h) * D_ + d) * L_ + l0 + l8) = o;
  }
}

// ---------------- Kernel 4: attention, gload_lds staging, lr-split waves -------
// Grid (L/64, H, B) = 1024 blocks -> 4 blocks/CU. Wave w: q-block (w>>1)*32,
// lr-subtile (w&1). Staging via global_load_lds (linear LDS dest, pre-swizzled
// global source); frag reads apply the same XOR. 1 barrier/chunk.
__global__ __launch_bounds__(256, 4) void k_attn(
    const short* __restrict__ Qw, const short* __restrict__ Kw,
    const short* __restrict__ Vtg, short* __restrict__ Ow) {
  int l0 = blockIdx.x * 64;
  int h  = blockIdx.y;
  int b  = blockIdx.z;
  __shared__ alignas(16) short SM[2][2][64 * 64];   // [buf][K|V][row][64]  32 KB
  int t = threadIdx.x, lane = t & 63, w = t >> 6;
  int l5 = lane & 31, hi = lane >> 5;
  int qsel = w >> 1;     // which 32-q block of the 64-q tile
  int Ts   = w & 1;      // which 32-lr subtile of each 64-lr chunk

  // Q fragments (B-operand: col=q=l5, k=d). Q already scaled by 0.125*log2e.
  short8 qf[4];
  {
    int qrow = b * L_ + l0 + qsel * 32 + l5;
    const short* qp = Qw + ((size_t)qrow * H_ + h) * D_ + hi * 8;
#pragma unroll
    for (int kc = 0; kc < 4; ++kc) qf[kc] = *(const short8*)(qp + kc * 16);
  }

  f32x16 acc[2];
#pragma unroll
  for (int dt = 0; dt < 2; ++dt)
#pragma unroll
    for (int r = 0; r < 16; ++r) acc[dt][r] = 0.f;
  float lsum = 0.f;

  const short* Kbase = Kw + (size_t)(b * L_) * C_ + h * D_;
  const short* Vbase = Vtg + (size_t)(b * H_ + h) * D_ * L_;

  int g0 = w * 8 + (lane >> 3);   // staging row (j=0); j=1 adds 32
  int gc = SW8(lane);             // swizzled source chunk (shorts)

  // prologue: stage chunk 0 into buffer 0
#pragma unroll
  for (int j = 0; j < 2; ++j) {
    int row = j * 32 + g0;
    gload16(Kbase + (size_t)row * C_ + gc, &SM[0][0][(j * 4 + w) * 512]);
    gload16(Vbase + (size_t)row * L_ + gc, &SM[0][1][(j * 4 + w) * 512]);
  }

  int cur = 0;
  for (int it = 0; it < 32; ++it) {
    __syncthreads();   // drains gload_lds (vmcnt) -> buf[cur] ready
    if (it < 31) {     // prefetch next chunk into other buffer (flies under compute)
      int lr0 = (it + 1) * 64;
#pragma unroll
      for (int j = 0; j < 2; ++j) {
        int row = j * 32 + g0;
        gload16(Kbase + (size_t)(lr0 + row) * C_ + gc, &SM[cur ^ 1][0][(j * 4 + w) * 512]);
        gload16(Vbase + (size_t)row * L_ + lr0 + gc, &SM[cur ^ 1][1][(j * 4 + w) * 512]);
      }
    }
    const short* KT = &SM[cur][0][0];
    const short* VT = &SM[cur][1][0];

    // --- frag reads (XOR on chunk index, matching staged layout)
    short8 kf[4];
#pragma unroll
    for (int kc = 0; kc < 4; ++kc) {
      int row = Ts * 32 + l5;
      kf[kc] = *(const short8*)(KT + row * 64 + (((kc * 2 + hi) ^ (row & 7)) << 3));
    }
    short8 va[2][2];
#pragma unroll
    for (int dt = 0; dt < 2; ++dt)
#pragma unroll
      for (int kc = 0; kc < 2; ++kc) {
        int row = dt * 32 + l5;
        va[dt][kc] = *(const short8*)(VT + row * 64 + ((((Ts * 2 + kc) * 2 + hi) ^ (row & 7)) << 3));
      }

    // --- S^T = K . Q^T   (this wave's 32-lr subtile only)
    f32x16 st;
#pragma unroll
    for (int r = 0; r < 16; ++r) st[r] = 0.f;
    __builtin_amdgcn_s_setprio(1);
#pragma unroll
    for (int kc = 0; kc < 4; ++kc)
      st = __builtin_amdgcn_mfma_f32_32x32x16_bf16(kf[kc], qf[kc], st, 0, 0, 0);
    __builtin_amdgcn_s_setprio(0);

    // --- softmax (unnormalized) + pack P^T B-frags in-register
    float ps[16];
#pragma unroll
    for (int r = 0; r < 16; ++r) {
      float u  = __builtin_amdgcn_fmed3f(st[r], -72.134752044448f, 72.134752044448f);
      float pv = __builtin_amdgcn_exp2f(u);
      lsum += pv;
      ps[r] = pv;
    }
    short8 pfrag[2];
    {
      unsigned d0 = cvtpk(ps[0], ps[1]),   d1 = cvtpk(ps[2], ps[3]);
      unsigned d2 = cvtpk(ps[4], ps[5]),   d3 = cvtpk(ps[6], ps[7]);
      pl32swap(d0, d2); pl32swap(d1, d3);
      pfrag[0] = mk8(d0, d1, d2, d3);
      unsigned e0 = cvtpk(ps[8], ps[9]),   e1 = cvtpk(ps[10], ps[11]);
      unsigned e2 = cvtpk(ps[12], ps[13]), e3 = cvtpk(ps[14], ps[15]);
      pl32swap(e0, e2); pl32swap(e1, e3);
      pfrag[1] = mk8(e0, e1, e2, e3);
    }

    // --- O^T(partial) += V^T . P^T
    __builtin_amdgcn_s_setprio(1);
#pragma unroll
    for (int dt = 0; dt < 2; ++dt)
#pragma unroll
      for (int kc = 0; kc < 2; ++kc)
        acc[dt] = __builtin_amdgcn_mfma_f32_32x32x16_bf16(va[dt][kc], pfrag[kc], acc[dt], 0, 0, 0);
    __builtin_amdgcn_s_setprio(0);

    cur ^= 1;
  }

  // --- epilogue: pair-reduce (odd wave -> even wave), normalize, store --------
  __syncthreads();                       // all chunk LDS reads done; reuse SM
  float* red = (float*)&SM[0][0][0];     // 2 pairs x 64 lanes x 34 f32 = 17408 B
  if (w & 1) {
    float* dst = red + (w >> 1) * (64 * 34) + lane * 34;
#pragma unroll
    for (int dt = 0; dt < 2; ++dt)
#pragma unroll
      for (int r = 0; r < 16; ++r) dst[dt * 16 + r] = acc[dt][r];
    dst[32] = lsum;
  }
  __syncthreads();
  if (!(w & 1)) {
    const float* srcp = red + (w >> 1) * (64 * 34) + lane * 34;
#pragma unroll
    for (int dt = 0; dt < 2; ++dt)
#pragma unroll
      for (int r = 0; r < 16; ++r) acc[dt][r] += srcp[dt * 16 + r];
    lsum += srcp[32];
    lsum += __shfl_xor(lsum, 32, 64);    // combine hi halves: full row sum
    float inv = 1.0f / lsum;
    short* ot = (short*)((char*)&SM[0][0][0] + 20480) + (w >> 1) * (32 * 72);
#pragma unroll
    for (int dt = 0; dt < 2; ++dt)
#pragma unroll
      for (int rq = 0; rq < 4; ++rq) {
        s4v o;
#pragma unroll
        for (int j = 0; j < 4; ++j) o[j] = f2bf(acc[dt][rq * 4 + j] * inv);
        *(s4v*)(ot + l5 * 72 + dt * 32 + rq * 8 + hi * 4) = o;
      }
#pragma unroll
    for (int p = 0; p < 4; ++p) {
      int rr = p * 8 + (lane >> 3);
      int c8b = (lane & 7) * 8;
      short8 v = *(const short8*)(ot + rr * 72 + c8b);
      int qg = b * L_ + l0 + (w >> 1) * 32 + rr;
      *(short8*)(Ow + ((size_t)qg * H_ + h) * D_ + c8b) = v;
    }
  }
}

// ---------------- Kernel 5: output projection + bias + residual + transpose ----
__global__ __launch_bounds__(256) void k_gemm_out(
    const short* __restrict__ Ow, const short* __restrict__ Wot,
    const float* __restrict__ bo, const short* __restrict__ qn,
    float* __restrict__ out) {
  int m0 = blockIdx.x * 128, n0 = blockIdx.y * 128;
  __shared__ alignas(16) short As[128 * 64];
  __shared__ alignas(16) short Bs[128 * 64];
  int t = threadIdx.x, lane = t & 63, w = t >> 6;
  int wm = w & 1, wn = w >> 1;
  int g0 = w * 8 + (lane >> 3);
  int gc = SW8(lane);

  f32x4 zero4 = {0.f, 0.f, 0.f, 0.f};
  f32x4 acc[4][4];
  for (int i = 0; i < 4; ++i) for (int j = 0; j < 4; ++j) acc[i][j] = zero4;

  for (int k0 = 0; k0 < C_; k0 += 64) {
    __syncthreads();
#pragma unroll
    for (int i = 0; i < 4; ++i) {
      int row = i * 32 + g0;
      gload16(Ow  + (size_t)(m0 + row) * C_ + k0 + gc, As + (i * 4 + w) * 512);
      gload16(Wot + (size_t)(n0 + row) * C_ + k0 + gc, Bs + (i * 4 + w) * 512);
    }
    __syncthreads();
#pragma unroll
    for (int kk = 0; kk < 2; ++kk) {
      short8 a[4], bf[4];
#pragma unroll
      for (int i = 0; i < 4; ++i) {
        int row = wm * 64 + i * 16 + (lane & 15);
        a[i] = *(const short8*)(As + row * 64 + (((kk * 4 + (lane >> 4)) ^ (row & 7)) << 3));
      }
#pragma unroll
      for (int i = 0; i < 4; ++i) {
        int row = wn * 64 + i * 16 + (lane & 15);
        bf[i] = *(const short8*)(Bs + row * 64 + (((kk * 4 + (lane >> 4)) ^ (row & 7)) << 3));
      }
#pragma unroll
      for (int i = 0; i < 4; ++i)
#pragma unroll
        for (int j = 0; j < 4; ++j)
          acc[i][j] = __builtin_amdgcn_mfma_f32_16x16x32_bf16(a[i], bf[j], acc[i][j], 0, 0, 0);
    }
  }

  for (int i = 0; i < 4; ++i)
    for (int j = 0; j < 4; ++j) {
      int colg = n0 + wn * 64 + j * 16 + (lane & 15);
      float bia = bo[colg];
      for (int r = 0; r < 4; ++r) {
        int rowg = m0 + wm * 64 + i * 16 + (lane >> 4) * 4 + r;
        float val = acc[i][j][r] + bia + bf2f(qn[(size_t)rowg * C_ + colg]);
        int bb = rowg >> 11, l = rowg & (L_ - 1);
        out[((size_t)bb * C_ + colg) * L_ + l] = val;   // (B, C, L)
      }
    }
}

extern "C" void kernel_launch(void* const* d_in, const int* in_sizes, int n_in,
                              void* d_out, int out_size, void* d_ws, size_t ws_size,
                              hipStream_t stream) {
  const float* query     = (const float*)d_in[0];
  const float* key_value = (const float*)d_in[1];
  const float* pos       = (const float*)d_in[2];
  const float* qg        = (const float*)d_in[3];
  const float* qb        = (const float*)d_in[4];
  const float* kg        = (const float*)d_in[5];
  const float* kb        = (const float*)d_in[6];
  const float* Wq        = (const float*)d_in[7];
  const float* bq        = (const float*)d_in[8];
  const float* Wk        = (const float*)d_in[9];
  const float* bk        = (const float*)d_in[10];
  const float* Wv        = (const float*)d_in[11];
  const float* bv        = (const float*)d_in[12];
  const float* Wo        = (const float*)d_in[13];
  const float* bo        = (const float*)d_in[14];
  float* out = (float*)d_out;

  char* ws = (char*)d_ws;
  const size_t SZ = (size_t)B_ * L_ * C_ * 2;   // 8 MB per bf16 (B,L,C) buffer
  short* qn  = (short*)(ws + 0 * SZ);
  short* kvn = (short*)(ws + 1 * SZ);
  short* Qw  = (short*)(ws + 2 * SZ);
  short* Kw  = (short*)(ws + 3 * SZ);
  short* Vw  = (short*)(ws + 4 * SZ);
  short* Ow  = (short*)(ws + 5 * SZ);
  short* Wt  = (short*)(ws + 6 * SZ);           // 4 x 512x512 bf16 = 2 MB
  short* Vtg = kvn;   // kvn dead after k_gemm_qkv; reuse for V^T [b][h][d][l]

  k_convert_w<<<dim3(4, 16, 16), 256, 0, stream>>>(Wq, Wk, Wv, Wo, Wt);
  k_prep<<<dim3(L_ / 32, B_, 2), 256, 0, stream>>>(query, key_value, pos, qg, qb, kg, kb, qn, kvn);
  k_gemm_qkv<<<dim3(8192 / 128, C_ / 128, 3), 256, 0, stream>>>(qn, kvn, Wt, bq, bk, bv, Qw, Kw, Vw);
  k_transpose_v<<<dim3(L_ / 64, H_, B_), 256, 0, stream>>>(Vw, Vtg);
  k_attn<<<dim3(L_ / 64, H_, B_), 256, 0, stream>>>(Qw, Kw, Vtg, Ow);
  k_gemm_out<<<dim3(8192 / 128, C_ / 128, 1), 256, 0, stream>>>(Ow, Wt + (size_t)3 * C_ * C_, bo, qn, out);
}